// Round 4
// baseline (3879.048 us; speedup 1.0000x reference)
//
#include <hip/hip_runtime.h>
#include <hip/hip_bf16.h>
#include <math.h>

#define N_NODES 50000
#define N_EDGES 800000
#define N_GRAPHS 1024
#define HD 128
#define NLAYERS 5
#define EDGE_IN 41
#define NT 3
#define LN_EPS 1e-5f

typedef unsigned int uint;
typedef unsigned short ushort;
typedef __attribute__((ext_vector_type(8))) short short8;
typedef __attribute__((ext_vector_type(16))) float f32x16;

__device__ __forceinline__ float silu_f(float v) { return v / (1.0f + __expf(-v)); }

// round-to-nearest-even f32 -> bf16 bits
__device__ __forceinline__ ushort f2bf(float f) {
    uint u = __float_as_uint(f);
    u = u + 0x7FFFu + ((u >> 16) & 1u);
    return (ushort)(u >> 16);
}
// pack two f32 into bf16x2 (lo,hi)
__device__ __forceinline__ uint pk2(float lo, float hi) {
    uint a = __float_as_uint(lo);
    uint b = __float_as_uint(hi);
    a = (a + 0x7FFFu + ((a >> 16) & 1u)) >> 16;
    b = (b + 0x7FFFu + ((b >> 16) & 1u)) & 0xFFFF0000u;
    return b | a;
}

__device__ __forceinline__ short8 ld16(const ushort* p) {
    union { int4 i; short8 s; } u;
    u.i = *(const int4*)p;
    return u.s;
}

__device__ __forceinline__ f32x16 mfma32(short8 a, short8 b, f32x16 c) {
    return __builtin_amdgcn_mfma_f32_32x32x16_bf16(a, b, c, 0, 0, 0);
}

// ---------------- zero ----------------
__global__ void k_zero(float* __restrict__ p, int n) {
    int i = blockIdx.x * 256 + threadIdx.x;
    if (i < n) p[i] = 0.0f;
}

// ---------------- weight swizzle (t-major fragment order) ----------------
// element ((t*16+s)*64+L)*8+j  <-  W[k = s*16 + (L>>5)*8 + j][n = t*32 + (L&31)]
// Serves as B-layout for W (k x n) AND as A-layout for W^T (n x k).
__global__ void k_swz_w1(const float* __restrict__ w1, ushort* __restrict__ w1s) {
    int i = blockIdx.x * 256 + threadIdx.x;            // 5 * 65536
    int l = i >> 16;
    int r = i & 65535;
    int j = r & 7, L = (r >> 3) & 63, s = (r >> 9) & 15, t = (r >> 13) & 7;
    int k = s * 16 + (L >> 5) * 8 + j;
    int n = t * 32 + (L & 31);
    w1s[i] = f2bf(w1[(size_t)l * 65536 + k * 256 + n]);
}
__global__ void k_swz_w2(const float* __restrict__ w2, ushort* __restrict__ w2s) {
    int i = blockIdx.x * 256 + threadIdx.x;            // 5 * 32768
    int l = i >> 15;
    int r = i & 32767;
    int j = r & 7, L = (r >> 3) & 63, s = (r >> 9) & 15, t = (r >> 13) & 3;
    int k = s * 16 + (L >> 5) * 8 + j;
    int n = t * 32 + (L & 31);
    w2s[i] = f2bf(w2[(size_t)l * 32768 + k * 128 + n]);
}

// ---------------- node embed: x = silu(LN(atom @ emb_w + emb_b)) ----------------
__global__ __launch_bounds__(128) void k_node_embed(
    const float* __restrict__ atom, const float* __restrict__ w,
    const float* __restrict__ b, const float* __restrict__ g,
    const float* __restrict__ bet, float* __restrict__ x, ushort* __restrict__ x_bf)
{
    int node = blockIdx.x;
    int h = threadIdx.x;
    float4 a = *(const float4*)(atom + (size_t)node * 4);
    float acc = b[h] + a.x * w[h] + a.y * w[HD + h] + a.z * w[2 * HD + h] + a.w * w[3 * HD + h];
    __shared__ float s1[2], s2[2];
    float sum = acc, sq = acc * acc;
    for (int off = 32; off > 0; off >>= 1) { sum += __shfl_down(sum, off); sq += __shfl_down(sq, off); }
    int wid = h >> 6, lane = h & 63;
    if (lane == 0) { s1[wid] = sum; s2[wid] = sq; }
    __syncthreads();
    float m = (s1[0] + s1[1]) * (1.0f / 128.0f);
    float v = (s2[0] + s2[1]) * (1.0f / 128.0f) - m * m;
    float y = (acc - m) * rsqrtf(v + LN_EPS) * g[h] + bet[h];
    y = silu_f(y);
    x[(size_t)node * HD + h] = y;
    x_bf[(size_t)node * HD + h] = f2bf(y);
}

// ---------------- edge embed -> bf16 ----------------
#define ETILE 32
__global__ __launch_bounds__(128) void k_edge_embed(
    const float* __restrict__ fea, const float* __restrict__ w,
    const float* __restrict__ b, ushort* __restrict__ e_bf)
{
    __shared__ float sf[ETILE][EDGE_IN + 1];
    int e0 = blockIdx.x * ETILE;
    int tid = threadIdx.x;
    for (int i = tid; i < ETILE * EDGE_IN; i += 128) {
        int m = i / EDGE_IN, k = i % EDGE_IN;
        sf[m][k] = fea[(size_t)(e0 + m) * EDGE_IN + k];
    }
    __syncthreads();
    float bb = b[tid];
    float acc[ETILE];
#pragma unroll
    for (int m = 0; m < ETILE; m++) acc[m] = bb;
    for (int k = 0; k < EDGE_IN; k++) {
        float wk = w[k * HD + tid];
#pragma unroll
        for (int m = 0; m < ETILE; m++) acc[m] += sf[m][k] * wk;
    }
#pragma unroll
    for (int m = 0; m < ETILE; m++)
        e_bf[(size_t)(e0 + m) * HD + tid] = f2bf(silu_f(acc[m]));
}

// ---------------- degree / graph counts ----------------
__global__ void k_count(const int* __restrict__ nbr_idx, float* __restrict__ cnt) {
    int i = blockIdx.x * 256 + threadIdx.x;
    if (i < N_EDGES) atomicAdd(&cnt[nbr_idx[2 * i + 1]], 1.0f);
}
__global__ void k_gcount(const int* __restrict__ bm, float* __restrict__ gcnt) {
    int i = blockIdx.x * 256 + threadIdx.x;
    if (i < N_NODES) atomicAdd(&gcnt[bm[i]], 1.0f);
}

// ---------------- fused conv layer (MFMA bf16, flipped GEMM1, no LDS m1) ----------------
// GEMM1 (flipped): m1^T[256x32] = W1^T @ concat^T, chunked 32 features at a time.
//   A-operand = W1^T (pre-swizzled), B-operand = concat^T (same gather loads as before).
//   C-layout: lane holds edge=l31, 16 features in regs -> already A-oriented for GEMM2.
// Cross-half fixup: features mod 8 in {4..7} live in lane L^32 -> 2 shfl_xor per 16-k step.
// GEMM2: m2[32x128] = silu(m1 @ W2 + b2) accumulated chunk-by-chunk; atomic scatter.
__global__ __launch_bounds__(64) void k_conv_mfma(
    const ushort* __restrict__ x_bf, const ushort* __restrict__ e_bf,
    const int* __restrict__ nbr_idx,
    const ushort* __restrict__ w1s, const float* __restrict__ b1,
    const ushort* __restrict__ w2s, const float* __restrict__ b2,
    float* __restrict__ aggr)
{
    __shared__ int sDst[32];

    int L = threadIdx.x;
    int l31 = L & 31, lhi = L >> 5;
    int e0 = blockIdx.x * 32;

    if (L < 32) sDst[L] = nbr_idx[2 * (e0 + L) + 1];
    int src = nbr_idx[2 * (e0 + l31)];
    const ushort* xb = x_bf + (size_t)src * HD + lhi * 8;
    const ushort* ep = e_bf + (size_t)(e0 + l31) * HD + lhi * 8;
    __syncthreads();

    // hold x-row fragments (reused by all 8 chunks); e-rows reloaded (contiguous, L2-hot)
    short8 xs[8];
#pragma unroll
    for (int s = 0; s < 8; ++s) xs[s] = ld16(xb + s * 16);

    f32x16 acc2[4];
#pragma unroll
    for (int t = 0; t < 4; ++t)
#pragma unroll
        for (int i = 0; i < 16; ++i) acc2[t][i] = 0.0f;

    for (int c2 = 0; c2 < 8; ++c2) {
        f32x16 a1;
#pragma unroll
        for (int i = 0; i < 16; ++i) a1[i] = 0.0f;

        const ushort* wa = w1s + c2 * 8192 + (size_t)L * 8;
#pragma unroll
        for (int s = 0; s < 8; ++s)
            a1 = mfma32(ld16(wa + s * 512), xs[s], a1);
#pragma unroll
        for (int s = 0; s < 8; ++s)
            a1 = mfma32(ld16(wa + 4096 + s * 512), ld16(ep + s * 16), a1);

        // bias + silu + pack to bf16 pairs
        // lane holds features f_local = 8g + 4*lhi + i (i=0..3) of edge l31
        uint Dw[4][2];
#pragma unroll
        for (int g = 0; g < 4; ++g) {
            float4 bb = *(const float4*)(b1 + c2 * 32 + g * 8 + lhi * 4);
            float v0 = silu_f(a1[4 * g + 0] + bb.x);
            float v1 = silu_f(a1[4 * g + 1] + bb.y);
            float v2 = silu_f(a1[4 * g + 2] + bb.z);
            float v3 = silu_f(a1[4 * g + 3] + bb.w);
            Dw[g][0] = pk2(v0, v1);
            Dw[g][1] = pk2(v2, v3);
        }

        // assemble GEMM2 A-frags for the 2 k-steps this chunk covers, feed GEMM2
#pragma unroll
        for (int ssl = 0; ssl < 2; ++ssl) {
            uint d0a = Dw[2 * ssl][0],     d0b = Dw[2 * ssl][1];
            uint d1a = Dw[2 * ssl + 1][0], d1b = Dw[2 * ssl + 1][1];
            // send what partner needs, receive what we need
            uint qa = lhi ? d0a : d1a;
            uint qb = lhi ? d0b : d1b;
            uint ra = (uint)__shfl_xor((int)qa, 32, 64);
            uint rb = (uint)__shfl_xor((int)qb, 32, 64);
            uint ka = lhi ? d1a : d0a;
            uint kb = lhi ? d1b : d0b;
            union { int4 i; short8 s; } f;
            f.i.x = (int)(lhi ? ra : ka);
            f.i.y = (int)(lhi ? rb : kb);
            f.i.z = (int)(lhi ? ka : ra);
            f.i.w = (int)(lhi ? kb : rb);

            int ss = 2 * c2 + ssl;
            const ushort* wb = w2s + ss * 512 + (size_t)L * 8;
#pragma unroll
            for (int t = 0; t < 4; ++t)
                acc2[t] = mfma32(f.s, ld16(wb + t * 8192), acc2[t]);
        }
    }

    // epilogue: bias + silu + coalesced atomic scatter
    int dstv[16];
#pragma unroll
    for (int r = 0; r < 16; ++r)
        dstv[r] = sDst[(r & 3) + ((r >> 2) << 3) + (lhi << 2)];
#pragma unroll
    for (int t = 0; t < 4; ++t) {
        float bv = b2[t * 32 + l31];
#pragma unroll
        for (int r = 0; r < 16; ++r)
            atomicAdd(aggr + (size_t)dstv[r] * HD + t * 32 + l31, silu_f(acc2[t][r] + bv));
    }
}

// ---------------- post: x = LN(x + aggr/cnt); emit bf16 ----------------
__global__ __launch_bounds__(128) void k_post(
    const float* __restrict__ aggr, const float* __restrict__ cnt,
    const float* __restrict__ g, const float* __restrict__ bet,
    float* __restrict__ x, ushort* __restrict__ x_bf)
{
    int node = blockIdx.x;
    int h = threadIdx.x;
    float inv = 1.0f / fmaxf(cnt[node], 1.0f);
    float acc = x[(size_t)node * HD + h] + aggr[(size_t)node * HD + h] * inv;
    __shared__ float s1[2], s2[2];
    float sum = acc, sq = acc * acc;
    for (int off = 32; off > 0; off >>= 1) { sum += __shfl_down(sum, off); sq += __shfl_down(sq, off); }
    int wid = h >> 6, lane = h & 63;
    if (lane == 0) { s1[wid] = sum; s2[wid] = sq; }
    __syncthreads();
    float m = (s1[0] + s1[1]) * (1.0f / 128.0f);
    float v = (s2[0] + s2[1]) * (1.0f / 128.0f) - m * m;
    float y = (acc - m) * rsqrtf(v + LN_EPS) * g[h] + bet[h];
    x[(size_t)node * HD + h] = y;
    x_bf[(size_t)node * HD + h] = f2bf(y);
}

// ---------------- graph pooling ----------------
__global__ __launch_bounds__(128) void k_gaggr(
    const float* __restrict__ x, const int* __restrict__ bm,
    float* __restrict__ crystal)
{
    int node = blockIdx.x;
    int h = threadIdx.x;
    atomicAdd(&crystal[(size_t)bm[node] * HD + h], x[(size_t)node * HD + h]);
}

// ---------------- readout MLP ----------------
__global__ __launch_bounds__(128) void k_readout(
    const float* __restrict__ crystal, const float* __restrict__ gcnt,
    const float* __restrict__ w1, const float* __restrict__ b1,
    const float* __restrict__ w2, const float* __restrict__ b2,
    const float* __restrict__ w3, const float* __restrict__ b3,
    float* __restrict__ out)
{
    int gph = blockIdx.x;
    int t = threadIdx.x;
    __shared__ float sc[HD], sh1[HD], sh2[64];
    float inv = 1.0f / fmaxf(gcnt[gph], 1.0f);
    sc[t] = crystal[(size_t)gph * HD + t] * inv;
    __syncthreads();
    float acc = b1[t];
    for (int k = 0; k < HD; k++) acc += sc[k] * w1[k * HD + t];
    sh1[t] = silu_f(acc);
    __syncthreads();
    if (t < 64) {
        float a2 = b2[t];
        for (int k = 0; k < HD; k++) a2 += sh1[k] * w2[k * 64 + t];
        sh2[t] = silu_f(a2);
    }
    __syncthreads();
    if (t < NT) {
        float a3 = b3[t];
        for (int k = 0; k < 64; k++) a3 += sh2[k] * w3[k * NT + t];
        out[(size_t)gph * NT + t] = a3;
    }
}

extern "C" void kernel_launch(void* const* d_in, const int* in_sizes, int n_in,
                              void* d_out, int out_size, void* d_ws, size_t ws_size,
                              hipStream_t stream)
{
    const float* atom_fea = (const float*)d_in[0];
    const float* nbr_fea  = (const float*)d_in[1];
    const int*   nbr_idx  = (const int*)d_in[2];
    const int*   bm       = (const int*)d_in[3];
    const float* emb_w    = (const float*)d_in[4];
    const float* emb_b    = (const float*)d_in[5];
    const float* emb_ln_g = (const float*)d_in[6];
    const float* emb_ln_b = (const float*)d_in[7];
    const float* edge_w   = (const float*)d_in[8];
    const float* edge_b   = (const float*)d_in[9];
    const float* conv_w1  = (const float*)d_in[10];
    const float* conv_b1  = (const float*)d_in[11];
    const float* conv_w2  = (const float*)d_in[12];
    const float* conv_b2  = (const float*)d_in[13];
    const float* ln_g     = (const float*)d_in[14];
    const float* ln_b     = (const float*)d_in[15];
    const float* out_w1   = (const float*)d_in[16];
    const float* out_b1   = (const float*)d_in[17];
    const float* out_w2   = (const float*)d_in[18];
    const float* out_b2   = (const float*)d_in[19];
    const float* out_w3   = (const float*)d_in[20];
    const float* out_b3   = (const float*)d_in[21];
    float* out = (float*)d_out;

    // ---- workspace layout (256B-aligned regions) ----
    char* base = (char*)d_ws;
    size_t off = 0;
    auto alloc = [&](size_t bytes) -> char* {
        char* p = base + off;
        off = (off + bytes + 255) & ~(size_t)255;
        return p;
    };
    float*  xbuf    = (float*) alloc((size_t)N_NODES * HD * 4);
    float*  aggr    = (float*) alloc((size_t)N_NODES * HD * 4);
    float*  cnt     = (float*) alloc((size_t)N_NODES * 4);
    float*  crystal = (float*) alloc((size_t)N_GRAPHS * HD * 4);
    float*  gcnt    = (float*) alloc((size_t)N_GRAPHS * 4);
    ushort* x_bf    = (ushort*)alloc((size_t)N_NODES * HD * 2);
    ushort* e_bf    = (ushort*)alloc((size_t)N_EDGES * HD * 2);
    ushort* w1s     = (ushort*)alloc((size_t)NLAYERS * 65536 * 2);
    ushort* w2s     = (ushort*)alloc((size_t)NLAYERS * 32768 * 2);

    // weights -> swizzled bf16
    k_swz_w1<<<(NLAYERS * 65536) / 256, 256, 0, stream>>>(conv_w1, w1s);
    k_swz_w2<<<(NLAYERS * 32768) / 256, 256, 0, stream>>>(conv_w2, w2s);

    // zero cnt + crystal + gcnt (contiguous region)
    int zn = N_NODES + N_GRAPHS * HD + N_GRAPHS + 128;
    k_zero<<<(zn + 255) / 256, 256, 0, stream>>>(cnt, zn);

    k_node_embed<<<N_NODES, 128, 0, stream>>>(atom_fea, emb_w, emb_b, emb_ln_g, emb_ln_b, xbuf, x_bf);
    k_edge_embed<<<N_EDGES / ETILE, 128, 0, stream>>>(nbr_fea, edge_w, edge_b, e_bf);
    k_count<<<N_EDGES / 256, 256, 0, stream>>>(nbr_idx, cnt);
    k_gcount<<<(N_NODES + 255) / 256, 256, 0, stream>>>(bm, gcnt);

    for (int l = 0; l < NLAYERS; ++l) {
        k_zero<<<(N_NODES * HD) / 256, 256, 0, stream>>>(aggr, N_NODES * HD);
        k_conv_mfma<<<N_EDGES / 32, 64, 0, stream>>>(
            x_bf, e_bf, nbr_idx,
            w1s + (size_t)l * 65536, conv_b1 + (size_t)l * 256,
            w2s + (size_t)l * 32768, conv_b2 + (size_t)l * 128,
            aggr);
        k_post<<<N_NODES, 128, 0, stream>>>(aggr, cnt, ln_g + (size_t)l * HD, ln_b + (size_t)l * HD, xbuf, x_bf);
    }

    k_gaggr<<<N_NODES, 128, 0, stream>>>(xbuf, bm, crystal);
    k_readout<<<N_GRAPHS, 128, 0, stream>>>(crystal, gcnt, out_w1, out_b1, out_w2, out_b2, out_w3, out_b3, out);
}